// Round 3
// baseline (647.535 us; speedup 1.0000x reference)
//
#include <hip/hip_runtime.h>
#include <hip/hip_bf16.h>
#include <stdint.h>

// Problem constants
#define TOK    8192      // B*S
#define DIN    4096
#define DOUT   4096
#define NEXP   8
#define RK     16
#define NRANK  128       // NEXP*RK
#define KE     4224      // DIN + NRANK (extended K)
#define SEQB   2048      // S (tokens per batch entry)
#define LSCALE 2.0f      // ALPHA/RANK
#define KSPLIT 4
#define KSLICE (DIN / KSPLIT)   // 1024

typedef __attribute__((ext_vector_type(8))) short bf8_t;   // 8 bf16 = 4 VGPRs
typedef __attribute__((ext_vector_type(4))) float f4_t;

__device__ __forceinline__ void async_copy16(const void* g, void* l) {
  __builtin_amdgcn_global_load_lds((const __attribute__((address_space(1))) void*)g,
                                   (__attribute__((address_space(3))) void*)l,
                                   16, 0, 0);
}

__device__ __forceinline__ ushort f2bf(float f) {
  __hip_bfloat16 h = __float2bfloat16(f);
  return *reinterpret_cast<ushort*>(&h);
}

// ---------- fused conversion kernel (fp32 -> bf16, memory-bound) ----------
#define R0 (TOK * DIN / 8)        // 4,194,304
#define R1 (DOUT * DIN / 8)       // 2,097,152
#define R2 (DOUT * NEXP * 2)      //    65,536
#define R3 (NRANK * DIN / 8)      //    65,536
#define RTOT (R0 + R1 + R2 + R3)  // 6,422,528  (= 25088 * 256)

__global__ __launch_bounds__(256)
void cvt_all_kernel(const float* __restrict__ x, const float* __restrict__ wb,
                    const float* __restrict__ lu, const float* __restrict__ ld,
                    ushort* __restrict__ Xe, ushort* __restrict__ Wc,
                    ushort* __restrict__ Ldb) {
  int i = blockIdx.x * 256 + threadIdx.x;
  const float* src;
  ushort* dst;
  if (i < R0) {
    int t = i >> 9;                    // DIN/8 = 512
    int c = (i & 511) * 8;
    src = x + (size_t)t * DIN + c;
    dst = Xe + (size_t)t * KE + c;
  } else if (i < R0 + R1) {
    int j = i - R0;
    int t = j >> 9;
    int c = (j & 511) * 8;
    src = wb + (size_t)t * DIN + c;
    dst = Wc + (size_t)t * KE + c;
  } else if (i < R0 + R1 + R2) {
    int j = i - (R0 + R1);
    int o = j >> 4;
    int rem = j & 15;
    int n = rem >> 1;
    int half = rem & 1;
    src = lu + ((size_t)n * DOUT + o) * RK + half * 8;
    dst = Wc + (size_t)o * KE + DIN + n * RK + half * 8;
  } else {
    int j = i - (R0 + R1 + R2);
    src = ld + (size_t)j * 8;
    dst = Ldb + (size_t)j * 8;
  }
  const float4* s = reinterpret_cast<const float4*>(src);
  float4 a = s[0], b = s[1];
  union { ushort u[8]; uint4 v; } o;
  o.u[0]=f2bf(a.x); o.u[1]=f2bf(a.y); o.u[2]=f2bf(a.z); o.u[3]=f2bf(a.w);
  o.u[4]=f2bf(b.x); o.u[5]=f2bf(b.y); o.u[6]=f2bf(b.z); o.u[7]=f2bf(b.w);
  *reinterpret_cast<uint4*>(dst) = o.v;
}

// ---------- 128x128 bf16 MFMA GEMM (m97 structure) — down-projection only ----------
template<int KLEN, int LDB, int MODE>
__global__ __launch_bounds__(256)
void gemm128(const ushort* __restrict__ A,
             const ushort* __restrict__ Bm,
             float* __restrict__ C) {
  __shared__ __align__(16) ushort As[128 * 32];
  __shared__ __align__(16) ushort Bs[128 * 32];

  const int tid  = threadIdx.x;
  const int wave = tid >> 6;
  const int lane = tid & 63;

  int bm, bn;
  if (MODE == 0) {
    int bid = blockIdx.x;
    int xcd = bid & 7;
    int idx = bid >> 3;
    int nt  = xcd * 4 + (idx & 3);
    int mt  = idx >> 2;
    bm = mt * 128;
    bn = nt * 128;
  } else {
    bm = blockIdx.y * 128;
    bn = blockIdx.x * 128;
  }
  const int wm = wave & 1, wn = wave >> 1;

  f4_t acc[4][4];
#pragma unroll
  for (int i = 0; i < 4; i++)
#pragma unroll
    for (int j = 0; j < 4; j++) acc[i][j] = (f4_t){0.f, 0.f, 0.f, 0.f};

  const int f0 = tid * 8;
  const int r0 = f0 >> 5, c0 = f0 & 31;
  const int f1 = (256 + tid) * 8;
  const int r1 = f1 >> 5, c1 = f1 & 31;
  const int l0 = (wave << 6) * 8;
  const int l1 = (256 + (wave << 6)) * 8;

  const ushort* Ar = As + (wm * 64 + (lane & 15)) * 32 + (lane >> 4) * 8;
  const ushort* Br = Bs + (wn * 64 + (lane & 15)) * 32 + (lane >> 4) * 8;

  const int kbase = (MODE == 1) ? blockIdx.z * KSLICE : 0;
  const int kend  = kbase + KLEN;

  for (int k0 = kbase; k0 < kend; k0 += 32) {
    __syncthreads();
    async_copy16(A  + (size_t)(bm + r0) * KE  + k0 + c0, (void*)(As + l0));
    async_copy16(A  + (size_t)(bm + r1) * KE  + k0 + c1, (void*)(As + l1));
    async_copy16(Bm + (size_t)(bn + r0) * LDB + k0 + c0, (void*)(Bs + l0));
    async_copy16(Bm + (size_t)(bn + r1) * LDB + k0 + c1, (void*)(Bs + l1));
    __syncthreads();
    bf8_t av[4], bv[4];
#pragma unroll
    for (int i = 0; i < 4; i++) av[i] = *(const bf8_t*)(Ar + i * 16 * 32);
#pragma unroll
    for (int j = 0; j < 4; j++) bv[j] = *(const bf8_t*)(Br + j * 16 * 32);
#pragma unroll
    for (int i = 0; i < 4; i++)
#pragma unroll
      for (int j = 0; j < 4; j++)
        acc[i][j] = __builtin_amdgcn_mfma_f32_16x16x32_bf16(av[i], bv[j], acc[i][j], 0, 0, 0);
  }

  if (MODE == 0) {
#pragma unroll
    for (int i = 0; i < 4; i++) {
      int row = bm + wm * 64 + i * 16 + (lane >> 4) * 4;
#pragma unroll
      for (int j = 0; j < 4; j++) {
        int col = bn + wn * 64 + j * 16 + (lane & 15);
#pragma unroll
        for (int rr = 0; rr < 4; rr++)
          C[(size_t)(row + rr) * DOUT + col] = acc[i][j][rr];
      }
    }
  } else {
    float* Dz = C + (size_t)blockIdx.z * TOK * NRANK;
#pragma unroll
    for (int i = 0; i < 4; i++) {
      int row = bm + wm * 64 + i * 16 + (lane >> 4) * 4;
#pragma unroll
      for (int j = 0; j < 4; j++) {
        int col = wn * 64 + j * 16 + (lane & 15);
#pragma unroll
        for (int rr = 0; rr < 4; rr++)
          Dz[(size_t)(row + rr) * NRANK + col] = acc[i][j][rr];
      }
    }
  }
}

// reduce split-K slices, scale by routing*LSCALE, pack bf16 into Xe extension cols
__global__ void scale_store_kernel(const float* __restrict__ D32,
                                   const float* __restrict__ rw,
                                   ushort* __restrict__ Xe) {
  int i = blockIdx.x * 256 + threadIdx.x;          // [0, TOK*NRANK/4)
  int t = i >> 5;                                  // token
  int g = (i & 31) * 4;                            // col base (4 cols, same expert)
  size_t base = (size_t)t * NRANK + g;
  const size_t ss = (size_t)TOK * NRANK;
  float4 a = *reinterpret_cast<const float4*>(D32 + base);
  float4 b = *reinterpret_cast<const float4*>(D32 + ss + base);
  float4 c = *reinterpret_cast<const float4*>(D32 + 2 * ss + base);
  float4 d = *reinterpret_cast<const float4*>(D32 + 3 * ss + base);
  int n = g >> 4;                                  // expert index
  int bb = t / SEQB;
  float s = rw[bb * NEXP + n] * LSCALE;
  union { ushort u[4]; uint2 v; } o;
  o.u[0] = f2bf((a.x + b.x + c.x + d.x) * s);
  o.u[1] = f2bf((a.y + b.y + c.y + d.y) * s);
  o.u[2] = f2bf((a.z + b.z + c.z + d.z) * s);
  o.u[3] = f2bf((a.w + b.w + c.w + d.w) * s);
  *reinterpret_cast<uint2*>(Xe + (size_t)t * KE + DIN + g) = o.v;
}

// ---------- 256x256 bf16 GEMM, BK=64 4-phase template schedule ----------
// C[m,n] = sum_k A[m,k]*B[n,k], A:[TOK,KE], B:[DOUT,KE] (B^T), fp32 out.
// Window W_t computes K-tile t (64 wide) from buf b=t&1. 4 phases (mh,ks) =
// (0,0),(0,1),(1,0),(1,1); each: {4-8 ds_read_b128 | stage issue} -> barrier ->
// setprio(1) 16 MFMA setprio(0) -> barrier. Uniform small read bursts let the
// cross-wave stagger overlap LDS service with MFMA (m196: the fine interleave
// is the lever). No manual lgkm drains / sched_barrier (m141, m97).
// Race-free stage ledger (every stage postdates a barrier sealing its slot's
// prior readers' drains):
//   p0: A_{b^1} h0+h1 <- tile t+1 A   (slot idle: read W_{t-1}, final barrier)
//   p2: B_b h0 <- tile t+2 B          (B_b reads done p0/p1, sealed p1 barrier)
//   p3: B_b h1 <- tile t+2 B
// End-of-window s_waitcnt vmcnt(4): drains t+1's A (+ older t+1 B), keeps
// t+2's B (4 loads) in flight across the barrier (never 0 until epilogue).
// LDS XOR-swizzle (round1/2-proven 0 conflicts): phys = logical ^
// ((logical>>7)&7)<<4; staged via pre-swizzled per-lane global source + linear
// global_load_lds dest; frag reads apply the same XOR (per-lane const offset).
#define NT64 (KE / 64)    // 66

__global__ __launch_bounds__(512, 2)
void gemm256(const ushort* __restrict__ A, const ushort* __restrict__ Bm,
             float* __restrict__ C) {
  __shared__ __align__(16) ushort As2[2][256 * 64];   // 2 x 32 KiB
  __shared__ __align__(16) ushort Bs2[2][256 * 64];   // 2 x 32 KiB

  const int tid  = threadIdx.x;
  const int w    = tid >> 6;        // wave 0..7
  const int lane = tid & 63;
  const int wm   = w >> 2;          // 0..1  (M half)
  const int wn   = w & 3;           // 0..3  (N quarter)

  // XCD-aware rectangular chunks (round-2 proven: FETCH 557->203 MB).
  const int bid = blockIdx.x;
  const int xg  = bid & 7;
  const int jj  = bid >> 3;                            // 0..63
  const int bm  = (((xg & 3) << 3) + (jj & 7)) << 8;   // mi*256, mi 0..31
  const int bn  = (((xg >> 2) << 3) + (jj >> 3)) << 8; // ni*256, ni 0..15

  f4_t acc[8][4];
#pragma unroll
  for (int i = 0; i < 8; ++i)
#pragma unroll
    for (int q = 0; q < 4; ++q) acc[i][q] = (f4_t){0.f, 0.f, 0.f, 0.f};

  // ---- frag-read geometry (swizzled; rows are 128 B) ----
  // logical byte = row*128 + (ks*4 + lane>>4)*16 ; phys slot = slot ^ (row&7).
  // row&7 == frow&7 (all frag base rows are multiples of 8/16).
  const int frow = lane & 15;
  const int cb0  = (((lane >> 4) ^ (frow & 7)) << 4);  // ks=0 column bytes
  const int cb1  = cb0 ^ 64;                           // ks=1 (slot bit2 flip)

  // ---- staging geometry (half-tile = 128 rows x 64 cols = 16 KiB) ----
  // dest (linear): byte s = w*1024 + r*8192 + lane*16 within half.
  // logical = s ^ ((lane>>3)<<4) -> row = w*8 + (lane>>3) + r*64,
  //                                col_el = ((lane&7)^(lane>>3))*8.
  const int rr0   = w * 8 + (lane >> 3);               // r=0 row in half
  const int colst = ((lane & 7) ^ (lane >> 3)) * 8;    // element column
  const int dst0  = w * 512;                           // element base in half

  const ushort* Ap = A  + (size_t)bm * KE;
  const ushort* Bp = Bm + (size_t)bn * KE;

  // stage one half (h) of K-tile kt of matrix Mp into LDS tile Ls
#define STG(Mp, Ls, h, kt) do {                                              \
    const ushort* s_ = (Mp) + (size_t)((h) * 128 + rr0) * KE                 \
                            + (size_t)(kt) * 64 + colst;                     \
    async_copy16(s_,                  (void*)((Ls) + (h) * 8192 + dst0));    \
    async_copy16(s_ + (size_t)64 * KE,(void*)((Ls) + (h) * 8192 + dst0 + 4096)); \
  } while (0)

  // prologue: t0 A(h0,h1), t0 B(h0,h1), t1 B(h0,h1)  -> 12 loads/thread
  STG(Ap, As2[0], 0, 0); STG(Ap, As2[0], 1, 0);
  STG(Bp, Bs2[0], 0, 0); STG(Bp, Bs2[0], 1, 0);
  STG(Bp, Bs2[1], 0, 1); STG(Bp, Bs2[1], 1, 1);
  asm volatile("s_waitcnt vmcnt(4)" ::: "memory");   // t0 landed; t1 B in flight
  __builtin_amdgcn_s_barrier();

  for (int t = 0; t < NT64; ++t) {
    const int b = t & 1;
    const char* Ab = (const char*)(As2[b]) + (wm * 128 + frow) * 128;
    const char* Bb = (const char*)(Bs2[b]) + (wn * 64 + frow) * 128;
    bf8_t bk0[4], bk1[4];

    // ---- p0: (mh=0, ks=0) ---- reads 8, stage t+1 A (4 loads)
    {
      bf8_t av[4];
#pragma unroll
      for (int f = 0; f < 4; ++f) av[f]  = *(const bf8_t*)(Ab + f * 2048 + cb0);
#pragma unroll
      for (int g = 0; g < 4; ++g) bk0[g] = *(const bf8_t*)(Bb + g * 2048 + cb0);
      if (t + 1 < NT64) { STG(Ap, As2[b ^ 1], 0, t + 1); STG(Ap, As2[b ^ 1], 1, t + 1); }
      __builtin_amdgcn_s_barrier();
      __builtin_amdgcn_s_setprio(1);
#pragma unroll
      for (int f = 0; f < 4; ++f)
#pragma unroll
        for (int g = 0; g < 4; ++g)
          acc[f][g] = __builtin_amdgcn_mfma_f32_16x16x32_bf16(av[f], bk0[g], acc[f][g], 0, 0, 0);
      __builtin_amdgcn_s_setprio(0);
      __builtin_amdgcn_s_barrier();
    }

    // ---- p1: (mh=0, ks=1) ---- reads 8
    {
      bf8_t av[4];
#pragma unroll
      for (int f = 0; f < 4; ++f) av[f]  = *(const bf8_t*)(Ab + f * 2048 + cb1);
#pragma unroll
      for (int g = 0; g < 4; ++g) bk1[g] = *(const bf8_t*)(Bb + g * 2048 + cb1);
      __builtin_amdgcn_s_barrier();
      __builtin_amdgcn_s_setprio(1);
#pragma unroll
      for (int f = 0; f < 4; ++f)
#pragma unroll
        for (int g = 0; g < 4; ++g)
          acc[f][g] = __builtin_amdgcn_mfma_f32_16x16x32_bf16(av[f], bk1[g], acc[f][g], 0, 0, 0);
      __builtin_amdgcn_s_setprio(0);
      __builtin_amdgcn_s_barrier();
    }

    // ---- p2: (mh=1, ks=0) ---- reads 4, stage t+2 B_h0
    {
      bf8_t av[4];
#pragma unroll
      for (int f = 0; f < 4; ++f) av[f] = *(const bf8_t*)(Ab + 8192 + f * 2048 + cb0);
      if (t + 2 < NT64) STG(Bp, Bs2[b], 0, t + 2);
      __builtin_amdgcn_s_barrier();
      __builtin_amdgcn_s_setprio(1);
#pragma unroll
      for (int f = 0; f < 4; ++f)
#pragma unroll
        for (int g = 0; g < 4; ++g)
          acc[4 + f][g] = __builtin_amdgcn_mfma_f32_16x16x32_bf16(av[f], bk0[g], acc[4 + f][g], 0, 0, 0);
      __builtin_amdgcn_s_setprio(0);
      __builtin_amdgcn_s_barrier();
    }

    // ---- p3: (mh=1, ks=1) ---- reads 4, stage t+2 B_h1; end-of-window vmcnt
    {
      bf8_t av[4];
#pragma unroll
      for (int f = 0; f < 4; ++f) av[f] = *(const bf8_t*)(Ab + 8192 + f * 2048 + cb1);
      if (t + 2 < NT64) STG(Bp, Bs2[b], 1, t + 2);
      __builtin_amdgcn_s_barrier();
      __builtin_amdgcn_s_setprio(1);
#pragma unroll
      for (int f = 0; f < 4; ++f)
#pragma unroll
        for (int g = 0; g < 4; ++g)
          acc[4 + f][g] = __builtin_amdgcn_mfma_f32_16x16x32_bf16(av[f], bk1[g], acc[4 + f][g], 0, 0, 0);
      __builtin_amdgcn_s_setprio(0);
      // counted vmcnt: require tile t+1 complete (its A staged at p0 this
      // window, its B staged last window); keep t+2's B (4 loads) in flight.
      if (t < NT64 - 2)       asm volatile("s_waitcnt vmcnt(4)" ::: "memory");
      else if (t == NT64 - 2) asm volatile("s_waitcnt vmcnt(0)" ::: "memory");
      __builtin_amdgcn_s_barrier();
    }
  }

  // epilogue: fp32 C write (C/D layout: col = lane&15, row = (lane>>4)*4 + rr)
#pragma unroll
  for (int i = 0; i < 8; ++i) {
    int row = bm + wm * 128 + (i >> 2) * 64 + (i & 3) * 16 + (lane >> 4) * 4;
#pragma unroll
    for (int q = 0; q < 4; ++q) {
      int col = bn + wn * 64 + q * 16 + (lane & 15);
#pragma unroll
      for (int rr = 0; rr < 4; ++rr)
        C[(size_t)(row + rr) * DOUT + col] = acc[i][q][rr];
    }
  }
#undef STG
}

extern "C" void kernel_launch(void* const* d_in, const int* in_sizes, int n_in,
                              void* d_out, int out_size, void* d_ws, size_t ws_size,
                              hipStream_t stream) {
  const float* x  = (const float*)d_in[0];
  const float* rw = (const float*)d_in[1];
  const float* wb = (const float*)d_in[2];
  const float* ld = (const float*)d_in[3];
  const float* lu = (const float*)d_in[4];
  float* out = (float*)d_out;

  // workspace layout (bf16 elements unless noted)
  ushort* Xe  = (ushort*)d_ws;                         // TOK*KE
  ushort* Wc  = Xe + (size_t)TOK * KE;                 // DOUT*KE
  ushort* Ldb = Wc + (size_t)DOUT * KE;                // NRANK*DIN
  float*  D32 = (float*)(Ldb + (size_t)NRANK * DIN);   // KSPLIT*TOK*NRANK fp32

  // one fused conversion dispatch (x, W_base, lora_up, lora_down -> bf16)
  cvt_all_kernel<<<RTOT / 256, 256, 0, stream>>>(x, wb, lu, ld, Xe, Wc, Ldb);

  // down-projection: D32[z] = Xe[:, z*1024:(z+1)*1024] @ Ld^T   (split-K)
  gemm128<KSLICE, DIN, 1><<<dim3(1, TOK / 128, KSPLIT), 256, 0, stream>>>(Xe, Ldb, D32);
  // reduce + routing scale + pack into Xe extension columns
  scale_store_kernel<<<TOK * NRANK / 4 / 256, 256, 0, stream>>>(D32, rw, Xe);
  // main GEMM: out = Xe[TOK,KE] @ Wc[DOUT,KE]^T  (256x256, BK=64 4-phase)
  gemm256<<<dim3((TOK / 256) * (DOUT / 256)), 512, 0, stream>>>(Xe, Wc, out);
}

// Round 4
// 576.144 us; speedup vs baseline: 1.1239x; 1.1239x over previous
//
#include <hip/hip_runtime.h>
#include <hip/hip_bf16.h>
#include <stdint.h>

// Problem constants
#define TOK    8192      // B*S
#define DIN    4096
#define DOUT   4096
#define NEXP   8
#define RK     16
#define NRANK  128       // NEXP*RK
#define KE     4224      // DIN + NRANK (extended K)
#define SEQB   2048      // S (tokens per batch entry)
#define LSCALE 2.0f      // ALPHA/RANK
#define KSPLIT 4
#define KSLICE (DIN / KSPLIT)   // 1024

typedef __attribute__((ext_vector_type(8))) short bf8_t;   // 8 bf16 = 4 VGPRs
typedef __attribute__((ext_vector_type(4))) float f4_t;

__device__ __forceinline__ void async_copy16(const void* g, void* l) {
  __builtin_amdgcn_global_load_lds((const __attribute__((address_space(1))) void*)g,
                                   (__attribute__((address_space(3))) void*)l,
                                   16, 0, 0);
}

__device__ __forceinline__ ushort f2bf(float f) {
  __hip_bfloat16 h = __float2bfloat16(f);
  return *reinterpret_cast<ushort*>(&h);
}

// ---------- fused conversion kernel (fp32 -> bf16, memory-bound) ----------
#define R0 (TOK * DIN / 8)        // 4,194,304
#define R1 (DOUT * DIN / 8)       // 2,097,152
#define R2 (DOUT * NEXP * 2)      //    65,536
#define R3 (NRANK * DIN / 8)      //    65,536
#define RTOT (R0 + R1 + R2 + R3)  // 6,422,528  (= 25088 * 256)

__global__ __launch_bounds__(256)
void cvt_all_kernel(const float* __restrict__ x, const float* __restrict__ wb,
                    const float* __restrict__ lu, const float* __restrict__ ld,
                    ushort* __restrict__ Xe, ushort* __restrict__ Wc,
                    ushort* __restrict__ Ldb) {
  int i = blockIdx.x * 256 + threadIdx.x;
  const float* src;
  ushort* dst;
  if (i < R0) {
    int t = i >> 9;                    // DIN/8 = 512
    int c = (i & 511) * 8;
    src = x + (size_t)t * DIN + c;
    dst = Xe + (size_t)t * KE + c;
  } else if (i < R0 + R1) {
    int j = i - R0;
    int t = j >> 9;
    int c = (j & 511) * 8;
    src = wb + (size_t)t * DIN + c;
    dst = Wc + (size_t)t * KE + c;
  } else if (i < R0 + R1 + R2) {
    int j = i - (R0 + R1);
    int o = j >> 4;
    int rem = j & 15;
    int n = rem >> 1;
    int half = rem & 1;
    src = lu + ((size_t)n * DOUT + o) * RK + half * 8;
    dst = Wc + (size_t)o * KE + DIN + n * RK + half * 8;
  } else {
    int j = i - (R0 + R1 + R2);
    src = ld + (size_t)j * 8;
    dst = Ldb + (size_t)j * 8;
  }
  const float4* s = reinterpret_cast<const float4*>(src);
  float4 a = s[0], b = s[1];
  union { ushort u[8]; uint4 v; } o;
  o.u[0]=f2bf(a.x); o.u[1]=f2bf(a.y); o.u[2]=f2bf(a.z); o.u[3]=f2bf(a.w);
  o.u[4]=f2bf(b.x); o.u[5]=f2bf(b.y); o.u[6]=f2bf(b.z); o.u[7]=f2bf(b.w);
  *reinterpret_cast<uint4*>(dst) = o.v;
}

// ---------- 128x128 bf16 MFMA GEMM (m97 structure) — down-projection only ----------
template<int KLEN, int LDB, int MODE>
__global__ __launch_bounds__(256)
void gemm128(const ushort* __restrict__ A,
             const ushort* __restrict__ Bm,
             float* __restrict__ C) {
  __shared__ __align__(16) ushort As[128 * 32];
  __shared__ __align__(16) ushort Bs[128 * 32];

  const int tid  = threadIdx.x;
  const int wave = tid >> 6;
  const int lane = tid & 63;

  int bm, bn;
  if (MODE == 0) {
    int bid = blockIdx.x;
    int xcd = bid & 7;
    int idx = bid >> 3;
    int nt  = xcd * 4 + (idx & 3);
    int mt  = idx >> 2;
    bm = mt * 128;
    bn = nt * 128;
  } else {
    bm = blockIdx.y * 128;
    bn = blockIdx.x * 128;
  }
  const int wm = wave & 1, wn = wave >> 1;

  f4_t acc[4][4];
#pragma unroll
  for (int i = 0; i < 4; i++)
#pragma unroll
    for (int j = 0; j < 4; j++) acc[i][j] = (f4_t){0.f, 0.f, 0.f, 0.f};

  const int f0 = tid * 8;
  const int r0 = f0 >> 5, c0 = f0 & 31;
  const int f1 = (256 + tid) * 8;
  const int r1 = f1 >> 5, c1 = f1 & 31;
  const int l0 = (wave << 6) * 8;
  const int l1 = (256 + (wave << 6)) * 8;

  const ushort* Ar = As + (wm * 64 + (lane & 15)) * 32 + (lane >> 4) * 8;
  const ushort* Br = Bs + (wn * 64 + (lane & 15)) * 32 + (lane >> 4) * 8;

  const int kbase = (MODE == 1) ? blockIdx.z * KSLICE : 0;
  const int kend  = kbase + KLEN;

  for (int k0 = kbase; k0 < kend; k0 += 32) {
    __syncthreads();
    async_copy16(A  + (size_t)(bm + r0) * KE  + k0 + c0, (void*)(As + l0));
    async_copy16(A  + (size_t)(bm + r1) * KE  + k0 + c1, (void*)(As + l1));
    async_copy16(Bm + (size_t)(bn + r0) * LDB + k0 + c0, (void*)(Bs + l0));
    async_copy16(Bm + (size_t)(bn + r1) * LDB + k0 + c1, (void*)(Bs + l1));
    __syncthreads();
    bf8_t av[4], bv[4];
#pragma unroll
    for (int i = 0; i < 4; i++) av[i] = *(const bf8_t*)(Ar + i * 16 * 32);
#pragma unroll
    for (int j = 0; j < 4; j++) bv[j] = *(const bf8_t*)(Br + j * 16 * 32);
#pragma unroll
    for (int i = 0; i < 4; i++)
#pragma unroll
      for (int j = 0; j < 4; j++)
        acc[i][j] = __builtin_amdgcn_mfma_f32_16x16x32_bf16(av[i], bv[j], acc[i][j], 0, 0, 0);
  }

  if (MODE == 0) {
#pragma unroll
    for (int i = 0; i < 4; i++) {
      int row = bm + wm * 64 + i * 16 + (lane >> 4) * 4;
#pragma unroll
      for (int j = 0; j < 4; j++) {
        int col = bn + wn * 64 + j * 16 + (lane & 15);
#pragma unroll
        for (int rr = 0; rr < 4; rr++)
          C[(size_t)(row + rr) * DOUT + col] = acc[i][j][rr];
      }
    }
  } else {
    float* Dz = C + (size_t)blockIdx.z * TOK * NRANK;
#pragma unroll
    for (int i = 0; i < 4; i++) {
      int row = bm + wm * 64 + i * 16 + (lane >> 4) * 4;
#pragma unroll
      for (int j = 0; j < 4; j++) {
        int col = wn * 64 + j * 16 + (lane & 15);
#pragma unroll
        for (int rr = 0; rr < 4; rr++)
          Dz[(size_t)(row + rr) * NRANK + col] = acc[i][j][rr];
      }
    }
  }
}

// reduce split-K slices, scale by routing*LSCALE, pack bf16 into Xe extension cols
__global__ void scale_store_kernel(const float* __restrict__ D32,
                                   const float* __restrict__ rw,
                                   ushort* __restrict__ Xe) {
  int i = blockIdx.x * 256 + threadIdx.x;          // [0, TOK*NRANK/4)
  int t = i >> 5;                                  // token
  int g = (i & 31) * 4;                            // col base (4 cols, same expert)
  size_t base = (size_t)t * NRANK + g;
  const size_t ss = (size_t)TOK * NRANK;
  float4 a = *reinterpret_cast<const float4*>(D32 + base);
  float4 b = *reinterpret_cast<const float4*>(D32 + ss + base);
  float4 c = *reinterpret_cast<const float4*>(D32 + 2 * ss + base);
  float4 d = *reinterpret_cast<const float4*>(D32 + 3 * ss + base);
  int n = g >> 4;                                  // expert index
  int bb = t / SEQB;
  float s = rw[bb * NEXP + n] * LSCALE;
  union { ushort u[4]; uint2 v; } o;
  o.u[0] = f2bf((a.x + b.x + c.x + d.x) * s);
  o.u[1] = f2bf((a.y + b.y + c.y + d.y) * s);
  o.u[2] = f2bf((a.z + b.z + c.z + d.z) * s);
  o.u[3] = f2bf((a.w + b.w + c.w + d.w) * s);
  *reinterpret_cast<uint2*>(Xe + (size_t)t * KE + DIN + g) = o.v;
}

// ---------- 256x256 bf16 GEMM, BK=32, one-phase-ahead pipelined schedule ----------
// C[m,n] = sum_k A[m,k]*B[n,k], A:[TOK,KE], B:[DOUT,KE] (B^T), fp32 out.
// Geometry/swizzle/staging identical to the round-2 kernel (proven: 0 bank
// conflicts, FETCH 203 MB, numerically correct). New: software-pipelined
// operand reads. Window t (K=32, slot b=t&3, ring-4), 2 phases:
//   p0: issue 4 ds_reads (mh1 A-frags, slot b) + stage A(t+2);
//       barrier; setprio1; 16 MFMA mh0 (frags read LAST phase); setprio0; barrier
//   p1: vmcnt(2) [tile t+1 resident]; issue 8 ds_reads (tile t+1 mh0 A + B);
//       stage B(t+2); barrier; setprio1; 16 MFMA mh1; setprio0; barrier
// Reads issued in phase p are consumed in phase p+1: the compiler's counted
// lgkmcnt (lgkm(4)/lgkm(8)) lets them stay in flight THROUGH the MFMA cluster,
// so LDS service overlaps MFMA instead of serializing with it. (r2/r3 measured
// phase = LDS 768 + MFMA 621 = 1390 cy — serial; target max(768,621)+eps.)
// Ping-pong frag sets indexed by compile-time u (unroll-by-2; rule #20: no
// runtime-indexed register arrays). No manual lgkm drains / sched_barrier.
// vmcnt ledger (4 staging loads/window: A@p0, B@p1): at p1 of window t the
// outstanding loads are A(t+1),B(t+1) [window t-1] and A(t+2) [this p0];
// vmcnt(2) drains tile t+1, keeps A(t+2) in flight. Tail: vmcnt(0).
#define NT32 (KE / 32)    // 132

__global__ __launch_bounds__(512, 2)
void gemm256(const ushort* __restrict__ A, const ushort* __restrict__ Bm,
             float* __restrict__ C) {
  __shared__ __align__(16) ushort As[4][256 * 32];   // 64 KiB
  __shared__ __align__(16) ushort Bs[4][256 * 32];   // 64 KiB

  const int tid  = threadIdx.x;
  const int w    = tid >> 6;        // wave 0..7
  const int lane = tid & 63;
  const int wm   = w >> 2;          // 0..1  (M half)
  const int wn   = w & 3;           // 0..3  (N quarter)

  // XCD-aware rectangular chunks (round-2 proven: FETCH 557->203 MB).
  const int bid = blockIdx.x;
  const int xg  = bid & 7;
  const int jj  = bid >> 3;                            // 0..63
  const int bm  = (((xg & 3) << 3) + (jj & 7)) << 8;   // mi*256, mi 0..31
  const int bn  = (((xg >> 2) << 3) + (jj >> 3)) << 8; // ni*256, ni 0..15

  f4_t acc[8][4];
#pragma unroll
  for (int i = 0; i < 8; ++i)
#pragma unroll
    for (int q = 0; q < 4; ++q) acc[i][q] = (f4_t){0.f, 0.f, 0.f, 0.f};

  // ---- frag-read geometry (swizzled; proven round 2) ----
  const int frow = lane & 15;
  const int cbs  = (((lane >> 4) ^ (frow >> 1)) << 4);
  const int ar0  = wm * 128;        // wave's A row base (rows)
  const int br0  = wn * 64;         // wave's B row base (rows)

  // ---- staging geometry (per-thread, tile = 256x32 bf16 = 16 KiB; proven) ----
  const int sxr = (lane >> 3) << 4;
  const int t0  = (w << 10) + (lane << 4);
  const int l0b = t0 ^ sxr;
  const int l1b = (t0 + 8192) ^ sxr;
  const size_t goff0 = (size_t)(l0b >> 6) * KE + ((l0b & 63) >> 1); // elements
  const size_t goff1 = (size_t)(l1b >> 6) * KE + ((l1b & 63) >> 1);
  const int ld0 = (w << 9);          // LDS dest base, elements
  const int ld1 = (w << 9) + 4096;

  const ushort* Ap = A  + (size_t)bm * KE;
  const ushort* Bp = Bm + (size_t)bn * KE;

#define STAGE_A256(kt, buf) do {                                   \
    const ushort* cp_ = Ap + (size_t)(kt) * 32;                    \
    async_copy16(cp_ + goff0, (void*)(As[buf] + ld0));             \
    async_copy16(cp_ + goff1, (void*)(As[buf] + ld1));             \
  } while (0)
#define STAGE_B256(kt, buf) do {                                   \
    const ushort* cp_ = Bp + (size_t)(kt) * 32;                    \
    async_copy16(cp_ + goff0, (void*)(Bs[buf] + ld0));             \
    async_copy16(cp_ + goff1, (void*)(Bs[buf] + ld1));             \
  } while (0)
// A-frag (mh half, index f_) / B-frag (index g_) read from slot s_
#define RD_A(s_, mh, f_) (*(const bf8_t*)((const char*)As[s_] + \
    (((ar0 + (mh) * 64 + (f_) * 16 + frow) << 6) ^ cbs)))
#define RD_B(s_, g_) (*(const bf8_t*)((const char*)Bs[s_] + \
    (((br0 + (g_) * 16 + frow) << 6) ^ cbs)))

  // prologue: stage tiles 0,1 into ring slots 0,1 (8 loads/thread).
  STAGE_A256(0, 0); STAGE_B256(0, 0);
  STAGE_A256(1, 1); STAGE_B256(1, 1);
  asm volatile("s_waitcnt vmcnt(4)" ::: "memory");   // tile 0 landed; 1 in flight
  __builtin_amdgcn_s_barrier();

  // ping-pong frag sets (static-indexed via unrolled u)
  bf8_t fA0[2][4], fA1[2][4], fB[2][4];
#pragma unroll
  for (int f = 0; f < 4; ++f) fA0[0][f] = RD_A(0, 0, f);
#pragma unroll
  for (int g = 0; g < 4; ++g) fB[0][g]  = RD_B(0, g);

  for (int t2 = 0; t2 < NT32; t2 += 2) {
#pragma unroll
    for (int u = 0; u < 2; ++u) {
      const int t  = t2 + u;
      const int b  = t & 3;
      const int sb = (t + 2) & 3;
      const int b1 = (t + 1) & 3;

      // ---- p0: issue mh1 A-reads (consumed next phase); stage A(t+2) ----
#pragma unroll
      for (int f = 0; f < 4; ++f) fA1[u][f] = RD_A(b, 1, f);
      if (t + 2 < NT32) STAGE_A256(t + 2, sb);
      __builtin_amdgcn_s_barrier();
      __builtin_amdgcn_s_setprio(1);
#pragma unroll
      for (int f = 0; f < 4; ++f)
#pragma unroll
        for (int g = 0; g < 4; ++g)
          acc[f][g] = __builtin_amdgcn_mfma_f32_16x16x32_bf16(fA0[u][f], fB[u][g], acc[f][g], 0, 0, 0);
      __builtin_amdgcn_s_setprio(0);
      __builtin_amdgcn_s_barrier();

      // ---- p1: tile t+1 resident after counted vmcnt; issue its mh0+B reads
      //      (consumed next window's p0); stage B(t+2) ----
      if (t + 2 < NT32) asm volatile("s_waitcnt vmcnt(2)" ::: "memory");
      else              asm volatile("s_waitcnt vmcnt(0)" ::: "memory");
      if (t + 1 < NT32) {
#pragma unroll
        for (int f = 0; f < 4; ++f) fA0[u ^ 1][f] = RD_A(b1, 0, f);
#pragma unroll
        for (int g = 0; g < 4; ++g) fB[u ^ 1][g]  = RD_B(b1, g);
      }
      if (t + 2 < NT32) STAGE_B256(t + 2, sb);
      __builtin_amdgcn_s_barrier();
      __builtin_amdgcn_s_setprio(1);
#pragma unroll
      for (int f = 0; f < 4; ++f)
#pragma unroll
        for (int g = 0; g < 4; ++g)
          acc[4 + f][g] = __builtin_amdgcn_mfma_f32_16x16x32_bf16(fA1[u][f], fB[u][g], acc[4 + f][g], 0, 0, 0);
      __builtin_amdgcn_s_setprio(0);
      __builtin_amdgcn_s_barrier();
    }
  }

  // epilogue: fp32 C write (C/D layout: col = lane&15, row = (lane>>4)*4 + rr)
#pragma unroll
  for (int i = 0; i < 8; ++i) {
    int row = bm + wm * 128 + i * 16 + (lane >> 4) * 4;
#pragma unroll
    for (int q = 0; q < 4; ++q) {
      int col = bn + wn * 64 + q * 16 + (lane & 15);
#pragma unroll
      for (int rr = 0; rr < 4; ++rr)
        C[(size_t)(row + rr) * DOUT + col] = acc[i][q][rr];
    }
  }
#undef STAGE_A256
#undef STAGE_B256
#undef RD_A
#undef RD_B
}

extern "C" void kernel_launch(void* const* d_in, const int* in_sizes, int n_in,
                              void* d_out, int out_size, void* d_ws, size_t ws_size,
                              hipStream_t stream) {
  const float* x  = (const float*)d_in[0];
  const float* rw = (const float*)d_in[1];
  const float* wb = (const float*)d_in[2];
  const float* ld = (const float*)d_in[3];
  const float* lu = (const float*)d_in[4];
  float* out = (float*)d_out;

  // workspace layout (bf16 elements unless noted)
  ushort* Xe  = (ushort*)d_ws;                         // TOK*KE
  ushort* Wc  = Xe + (size_t)TOK * KE;                 // DOUT*KE
  ushort* Ldb = Wc + (size_t)DOUT * KE;                // NRANK*DIN
  float*  D32 = (float*)(Ldb + (size_t)NRANK * DIN);   // KSPLIT*TOK*NRANK fp32

  // one fused conversion dispatch (x, W_base, lora_up, lora_down -> bf16)
  cvt_all_kernel<<<RTOT / 256, 256, 0, stream>>>(x, wb, lu, ld, Xe, Wc, Ldb);

  // down-projection: D32[z] = Xe[:, z*1024:(z+1)*1024] @ Ld^T   (split-K)
  gemm128<KSLICE, DIN, 1><<<dim3(1, TOK / 128, KSPLIT), 256, 0, stream>>>(Xe, Ldb, D32);
  // reduce + routing scale + pack into Xe extension columns
  scale_store_kernel<<<TOK * NRANK / 4 / 256, 256, 0, stream>>>(D32, rw, Xe);
  // main GEMM: out = Xe[TOK,KE] @ Wc[DOUT,KE]^T  (256x256, pipelined BK=32)
  gemm256<<<dim3((TOK / 256) * (DOUT / 256)), 512, 0, stream>>>(Xe, Wc, out);
}

// Round 5
// 573.691 us; speedup vs baseline: 1.1287x; 1.0043x over previous
//
#include <hip/hip_runtime.h>
#include <hip/hip_bf16.h>
#include <stdint.h>

// Problem constants
#define TOK    8192      // B*S
#define DIN    4096
#define DOUT   4096
#define NEXP   8
#define RK     16
#define NRANK  128       // NEXP*RK
#define KE     4224      // DIN + NRANK (extended K)
#define SEQB   2048      // S (tokens per batch entry)
#define LSCALE 2.0f      // ALPHA/RANK
#define KSPLIT 4
#define KSLICE (DIN / KSPLIT)   // 1024

typedef __attribute__((ext_vector_type(8))) short bf8_t;   // 8 bf16 = 4 VGPRs
typedef __attribute__((ext_vector_type(4))) float f4_t;

__device__ __forceinline__ void async_copy16(const void* g, void* l) {
  __builtin_amdgcn_global_load_lds((const __attribute__((address_space(1))) void*)g,
                                   (__attribute__((address_space(3))) void*)l,
                                   16, 0, 0);
}

__device__ __forceinline__ ushort f2bf(float f) {
  __hip_bfloat16 h = __float2bfloat16(f);
  return *reinterpret_cast<ushort*>(&h);
}

// ---------- fused conversion kernel (fp32 -> bf16, memory-bound) ----------
#define R0 (TOK * DIN / 8)        // 4,194,304
#define R1 (DOUT * DIN / 8)       // 2,097,152
#define R2 (DOUT * NEXP * 2)      //    65,536
#define R3 (NRANK * DIN / 8)      //    65,536
#define RTOT (R0 + R1 + R2 + R3)  // 6,422,528  (= 25088 * 256)

__global__ __launch_bounds__(256)
void cvt_all_kernel(const float* __restrict__ x, const float* __restrict__ wb,
                    const float* __restrict__ lu, const float* __restrict__ ld,
                    ushort* __restrict__ Xe, ushort* __restrict__ Wc,
                    ushort* __restrict__ Ldb) {
  int i = blockIdx.x * 256 + threadIdx.x;
  const float* src;
  ushort* dst;
  if (i < R0) {
    int t = i >> 9;                    // DIN/8 = 512
    int c = (i & 511) * 8;
    src = x + (size_t)t * DIN + c;
    dst = Xe + (size_t)t * KE + c;
  } else if (i < R0 + R1) {
    int j = i - R0;
    int t = j >> 9;
    int c = (j & 511) * 8;
    src = wb + (size_t)t * DIN + c;
    dst = Wc + (size_t)t * KE + c;
  } else if (i < R0 + R1 + R2) {
    int j = i - (R0 + R1);
    int o = j >> 4;
    int rem = j & 15;
    int n = rem >> 1;
    int half = rem & 1;
    src = lu + ((size_t)n * DOUT + o) * RK + half * 8;
    dst = Wc + (size_t)o * KE + DIN + n * RK + half * 8;
  } else {
    int j = i - (R0 + R1 + R2);
    src = ld + (size_t)j * 8;
    dst = Ldb + (size_t)j * 8;
  }
  const float4* s = reinterpret_cast<const float4*>(src);
  float4 a = s[0], b = s[1];
  union { ushort u[8]; uint4 v; } o;
  o.u[0]=f2bf(a.x); o.u[1]=f2bf(a.y); o.u[2]=f2bf(a.z); o.u[3]=f2bf(a.w);
  o.u[4]=f2bf(b.x); o.u[5]=f2bf(b.y); o.u[6]=f2bf(b.z); o.u[7]=f2bf(b.w);
  *reinterpret_cast<uint4*>(dst) = o.v;
}

// ---------- 128x128 bf16 MFMA GEMM (m97 structure) — down-projection only ----------
template<int KLEN, int LDB, int MODE>
__global__ __launch_bounds__(256)
void gemm128(const ushort* __restrict__ A,
             const ushort* __restrict__ Bm,
             float* __restrict__ C) {
  __shared__ __align__(16) ushort As[128 * 32];
  __shared__ __align__(16) ushort Bs[128 * 32];

  const int tid  = threadIdx.x;
  const int wave = tid >> 6;
  const int lane = tid & 63;

  int bm, bn;
  if (MODE == 0) {
    int bid = blockIdx.x;
    int xcd = bid & 7;
    int idx = bid >> 3;
    int nt  = xcd * 4 + (idx & 3);
    int mt  = idx >> 2;
    bm = mt * 128;
    bn = nt * 128;
  } else {
    bm = blockIdx.y * 128;
    bn = blockIdx.x * 128;
  }
  const int wm = wave & 1, wn = wave >> 1;

  f4_t acc[4][4];
#pragma unroll
  for (int i = 0; i < 4; i++)
#pragma unroll
    for (int j = 0; j < 4; j++) acc[i][j] = (f4_t){0.f, 0.f, 0.f, 0.f};

  const int f0 = tid * 8;
  const int r0 = f0 >> 5, c0 = f0 & 31;
  const int f1 = (256 + tid) * 8;
  const int r1 = f1 >> 5, c1 = f1 & 31;
  const int l0 = (wave << 6) * 8;
  const int l1 = (256 + (wave << 6)) * 8;

  const ushort* Ar = As + (wm * 64 + (lane & 15)) * 32 + (lane >> 4) * 8;
  const ushort* Br = Bs + (wn * 64 + (lane & 15)) * 32 + (lane >> 4) * 8;

  const int kbase = (MODE == 1) ? blockIdx.z * KSLICE : 0;
  const int kend  = kbase + KLEN;

  for (int k0 = kbase; k0 < kend; k0 += 32) {
    __syncthreads();
    async_copy16(A  + (size_t)(bm + r0) * KE  + k0 + c0, (void*)(As + l0));
    async_copy16(A  + (size_t)(bm + r1) * KE  + k0 + c1, (void*)(As + l1));
    async_copy16(Bm + (size_t)(bn + r0) * LDB + k0 + c0, (void*)(Bs + l0));
    async_copy16(Bm + (size_t)(bn + r1) * LDB + k0 + c1, (void*)(Bs + l1));
    __syncthreads();
    bf8_t av[4], bv[4];
#pragma unroll
    for (int i = 0; i < 4; i++) av[i] = *(const bf8_t*)(Ar + i * 16 * 32);
#pragma unroll
    for (int j = 0; j < 4; j++) bv[j] = *(const bf8_t*)(Br + j * 16 * 32);
#pragma unroll
    for (int i = 0; i < 4; i++)
#pragma unroll
      for (int j = 0; j < 4; j++)
        acc[i][j] = __builtin_amdgcn_mfma_f32_16x16x32_bf16(av[i], bv[j], acc[i][j], 0, 0, 0);
  }

  if (MODE == 0) {
#pragma unroll
    for (int i = 0; i < 4; i++) {
      int row = bm + wm * 64 + i * 16 + (lane >> 4) * 4;
#pragma unroll
      for (int j = 0; j < 4; j++) {
        int col = bn + wn * 64 + j * 16 + (lane & 15);
#pragma unroll
        for (int rr = 0; rr < 4; rr++)
          C[(size_t)(row + rr) * DOUT + col] = acc[i][j][rr];
      }
    }
  } else {
    float* Dz = C + (size_t)blockIdx.z * TOK * NRANK;
#pragma unroll
    for (int i = 0; i < 4; i++) {
      int row = bm + wm * 64 + i * 16 + (lane >> 4) * 4;
#pragma unroll
      for (int j = 0; j < 4; j++) {
        int col = wn * 64 + j * 16 + (lane & 15);
#pragma unroll
        for (int rr = 0; rr < 4; rr++)
          Dz[(size_t)(row + rr) * NRANK + col] = acc[i][j][rr];
      }
    }
  }
}

// reduce split-K slices, scale by routing*LSCALE, pack bf16 into Xe extension cols
__global__ void scale_store_kernel(const float* __restrict__ D32,
                                   const float* __restrict__ rw,
                                   ushort* __restrict__ Xe) {
  int i = blockIdx.x * 256 + threadIdx.x;          // [0, TOK*NRANK/4)
  int t = i >> 5;                                  // token
  int g = (i & 31) * 4;                            // col base (4 cols, same expert)
  size_t base = (size_t)t * NRANK + g;
  const size_t ss = (size_t)TOK * NRANK;
  float4 a = *reinterpret_cast<const float4*>(D32 + base);
  float4 b = *reinterpret_cast<const float4*>(D32 + ss + base);
  float4 c = *reinterpret_cast<const float4*>(D32 + 2 * ss + base);
  float4 d = *reinterpret_cast<const float4*>(D32 + 3 * ss + base);
  int n = g >> 4;                                  // expert index
  int bb = t / SEQB;
  float s = rw[bb * NEXP + n] * LSCALE;
  union { ushort u[4]; uint2 v; } o;
  o.u[0] = f2bf((a.x + b.x + c.x + d.x) * s);
  o.u[1] = f2bf((a.y + b.y + c.y + d.y) * s);
  o.u[2] = f2bf((a.z + b.z + c.z + d.z) * s);
  o.u[3] = f2bf((a.w + b.w + c.w + d.w) * s);
  *reinterpret_cast<uint2*>(Xe + (size_t)t * KE + DIN + g) = o.v;
}

// ---------- 256x256 bf16 GEMM, template phase structure (round-1 minus poison) ----------
// C[m,n] = sum_k A[m,k]*B[n,k], A:[TOK,KE], B:[DOUT,KE] (B^T), fp32 out.
// EXPERIMENT (single variable vs round 1): the sched_barrier(0) after each
// lgkmcnt(0) is REMOVED (m141: that exact order-pin measured -42%; rule #18
// requires it only for inline-asm ds_reads — ours are compiler-visible).
// Everything else is round-1 verbatim (template phase: {reads+stage ->
// barrier -> asm lgkmcnt(0) -> setprio(1) 16 MFMA setprio(0) -> barrier},
// 8/4 read split, ring-4 slots, 3-tile prefetch, vmcnt(8) steady cadence),
// plus round-2's proven rectangular XCD map (FETCH 557->203 MB).
// LDS XOR-swizzle (rounds 1-4: SQ_LDS_BANK_CONFLICT = 0) unchanged.
#define BK32  32
#define NT132 (KE / BK32)    // 132

__global__ __launch_bounds__(512, 2)
void gemm256(const ushort* __restrict__ A, const ushort* __restrict__ Bm,
             float* __restrict__ C) {
  __shared__ __align__(16) ushort As[4][256 * 32];   // 64 KiB
  __shared__ __align__(16) ushort Bs[4][256 * 32];   // 64 KiB

  const int tid  = threadIdx.x;
  const int w    = tid >> 6;        // wave 0..7
  const int lane = tid & 63;
  const int wm   = w >> 2;          // 0..1  (M half)
  const int wn   = w & 3;           // 0..3  (N quarter)

  // XCD-aware rectangular chunks (round-2 proven: FETCH 557->203 MB).
  const int bid = blockIdx.x;
  const int xg  = bid & 7;
  const int jj  = bid >> 3;                            // 0..63
  const int bm  = (((xg & 3) << 3) + (jj & 7)) << 8;   // mi*256, mi 0..31
  const int bn  = (((xg >> 2) << 3) + (jj >> 3)) << 8; // ni*256, ni 0..15

  f4_t acc[8][4];
#pragma unroll
  for (int i = 0; i < 8; ++i)
#pragma unroll
    for (int q = 0; q < 4; ++q) acc[i][q] = (f4_t){0.f, 0.f, 0.f, 0.f};

  // ---- frag-read geometry (swizzled; proven 0 conflicts) ----
  const int frow = lane & 15;
  const int cbs  = (((lane >> 4) ^ (frow >> 1)) << 4);
  const int ar0  = wm * 128;        // wave's A row base (rows)
  const int br0  = wn * 64;         // wave's B row base (rows)

  // ---- staging geometry (per-thread, tile = 256x32 bf16 = 16 KiB; proven) ----
  const int sxr = (lane >> 3) << 4;
  const int t0  = (w << 10) + (lane << 4);
  const int l0b = t0 ^ sxr;
  const int l1b = (t0 + 8192) ^ sxr;
  const size_t goff0 = (size_t)(l0b >> 6) * KE + ((l0b & 63) >> 1); // elements
  const size_t goff1 = (size_t)(l1b >> 6) * KE + ((l1b & 63) >> 1);
  const int ld0 = (w << 9);          // LDS dest base, elements
  const int ld1 = (w << 9) + 4096;

  const ushort* Ap = A  + (size_t)bm * KE;
  const ushort* Bp = Bm + (size_t)bn * KE;

#define STAGE_A256(kt, buf) do {                                   \
    const ushort* cp_ = Ap + (size_t)(kt) * BK32;                  \
    async_copy16(cp_ + goff0, (void*)(As[buf] + ld0));             \
    async_copy16(cp_ + goff1, (void*)(As[buf] + ld1));             \
  } while (0)
#define STAGE_B256(kt, buf) do {                                   \
    const ushort* cp_ = Bp + (size_t)(kt) * BK32;                  \
    async_copy16(cp_ + goff0, (void*)(Bs[buf] + ld0));             \
    async_copy16(cp_ + goff1, (void*)(Bs[buf] + ld1));             \
  } while (0)

  // prologue: stage tiles 0,1,2 into ring slots 0,1,2 (12 loads/thread).
  STAGE_A256(0, 0); STAGE_B256(0, 0);
  STAGE_A256(1, 1); STAGE_B256(1, 1);
  STAGE_A256(2, 2); STAGE_B256(2, 2);
  asm volatile("s_waitcnt vmcnt(8)" ::: "memory");   // tile 0 landed; 1,2 in flight
  __builtin_amdgcn_s_barrier();

  for (int T = 0; T < NT132; ++T) {
    const int b  = T & 3;
    const int sb = (T + 3) & 3;
    const char* Ab = (const char*)As[b];
    const char* Bb = (const char*)Bs[b];
    bf8_t a0[4], a1[4], bv[4];

    // ---- phase 0: read A(mh=0) 4 + B 4 frags; stage A-tile T+3; MFMA mh=0 ----
#pragma unroll
    for (int f = 0; f < 4; ++f)
      a0[f] = *(const bf8_t*)(Ab + (((ar0 + f * 16 + frow) << 6) ^ cbs));
#pragma unroll
    for (int g = 0; g < 4; ++g)
      bv[g] = *(const bf8_t*)(Bb + (((br0 + g * 16 + frow) << 6) ^ cbs));
    if (T + 3 < NT132) STAGE_A256(T + 3, sb);
    __builtin_amdgcn_s_barrier();
    asm volatile("s_waitcnt lgkmcnt(0)" ::: "memory");
    __builtin_amdgcn_s_setprio(1);
#pragma unroll
    for (int f = 0; f < 4; ++f)
#pragma unroll
      for (int g = 0; g < 4; ++g)
        acc[f][g] = __builtin_amdgcn_mfma_f32_16x16x32_bf16(a0[f], bv[g], acc[f][g], 0, 0, 0);
    __builtin_amdgcn_s_setprio(0);
    __builtin_amdgcn_s_barrier();

    // ---- phase 1: read A(mh=1) 4 frags; stage B-tile T+3; MFMA mh=1 ----
#pragma unroll
    for (int f = 0; f < 4; ++f)
      a1[f] = *(const bf8_t*)(Ab + (((ar0 + 64 + f * 16 + frow) << 6) ^ cbs));
    if (T + 3 < NT132) STAGE_B256(T + 3, sb);
    __builtin_amdgcn_s_barrier();
    asm volatile("s_waitcnt lgkmcnt(0)" ::: "memory");
    __builtin_amdgcn_s_setprio(1);
#pragma unroll
    for (int f = 0; f < 4; ++f)
#pragma unroll
      for (int g = 0; g < 4; ++g)
        acc[4 + f][g] = __builtin_amdgcn_mfma_f32_16x16x32_bf16(a1[f], bv[g], acc[4 + f][g], 0, 0, 0);
    __builtin_amdgcn_s_setprio(0);
    // counted vmcnt once per tile: keep the 8 newest loads (tiles T+2, T+3)
    // in flight; guarantees tile T+1 is fully in LDS before its phase-0 reads.
    if (T < NT132 - 3)       asm volatile("s_waitcnt vmcnt(8)" ::: "memory");
    else if (T == NT132 - 3) asm volatile("s_waitcnt vmcnt(4)" ::: "memory");
    else if (T == NT132 - 2) asm volatile("s_waitcnt vmcnt(0)" ::: "memory");
    __builtin_amdgcn_s_barrier();
  }

  // epilogue: fp32 C write (C/D layout: col = lane&15, row = (lane>>4)*4 + rr)
#pragma unroll
  for (int i = 0; i < 8; ++i) {
    int row = bm + wm * 128 + i * 16 + (lane >> 4) * 4;
#pragma unroll
    for (int q = 0; q < 4; ++q) {
      int col = bn + wn * 64 + q * 16 + (lane & 15);
#pragma unroll
      for (int rr = 0; rr < 4; ++rr)
        C[(size_t)(row + rr) * DOUT + col] = acc[i][q][rr];
    }
  }
#undef STAGE_A256
#undef STAGE_B256
}

extern "C" void kernel_launch(void* const* d_in, const int* in_sizes, int n_in,
                              void* d_out, int out_size, void* d_ws, size_t ws_size,
                              hipStream_t stream) {
  const float* x  = (const float*)d_in[0];
  const float* rw = (const float*)d_in[1];
  const float* wb = (const float*)d_in[2];
  const float* ld = (const float*)d_in[3];
  const float* lu = (const float*)d_in[4];
  float* out = (float*)d_out;

  // workspace layout (bf16 elements unless noted)
  ushort* Xe  = (ushort*)d_ws;                         // TOK*KE
  ushort* Wc  = Xe + (size_t)TOK * KE;                 // DOUT*KE
  ushort* Ldb = Wc + (size_t)DOUT * KE;                // NRANK*DIN
  float*  D32 = (float*)(Ldb + (size_t)NRANK * DIN);   // KSPLIT*TOK*NRANK fp32

  // one fused conversion dispatch (x, W_base, lora_up, lora_down -> bf16)
  cvt_all_kernel<<<RTOT / 256, 256, 0, stream>>>(x, wb, lu, ld, Xe, Wc, Ldb);

  // down-projection: D32[z] = Xe[:, z*1024:(z+1)*1024] @ Ld^T   (split-K)
  gemm128<KSLICE, DIN, 1><<<dim3(1, TOK / 128, KSPLIT), 256, 0, stream>>>(Xe, Ldb, D32);
  // reduce + routing scale + pack into Xe extension columns
  scale_store_kernel<<<TOK * NRANK / 4 / 256, 256, 0, stream>>>(D32, rw, Xe);
  // main GEMM: out = Xe[TOK,KE] @ Wc[DOUT,KE]^T  (256x256 template schedule)
  gemm256<<<dim3((TOK / 256) * (DOUT / 256)), 512, 0, stream>>>(Xe, Wc, out);
}